// Round 14
// baseline (394.185 us; speedup 1.0000x reference)
//
#include <hip/hip_runtime.h>
#include <math.h>

#define NPOW 88
#define NCO  85

// Single-kernel whole-network. Per-batch producer/consumer via device-scope atomics.
// ws layout: ctx[32*1536] | final[32*3840] | hpart[32*8*256] | cnt1[32] cnt2[32] cnt3[32]
// Roles (role-major block order):
//   idx   0..95   : A-scene   (b=idx/3, slice=idx%3)   scan+eval -> ctx[0:768],   inc cnt1[b]
//   idx  96..191  : A-speaker (j=idx-96)               scan+eval -> ctx[768:1536],inc cnt1[b]
//   idx 192..479  : B-fused   (j=idx-192, b=j/9,y=j%9) wait cnt1==6, -> final[y*256..], inc cnt2[b]
//   idx 480..575  : B-proj    (j=idx-480, b=j/3,p=j%3) p>0 waits cnt1==6, -> final[2304+p*512..], inc cnt2[b]
//   idx 576..831  : C-mlp     (j=idx-576, b=j/8,c=j%8) wait cnt2==12, chunk -> hpart; last does tail -> out

__device__ __forceinline__ float red32f(float x) {
    x += __shfl_xor(x, 1, 64);
    x += __shfl_xor(x, 2, 64);
    x += __shfl_xor(x, 4, 64);
    x += __shfl_xor(x, 8, 64);
    x += __shfl_xor(x, 16, 64);
    return x;
}

__device__ __forceinline__ void signal_cnt(int* cnt) {
    __threadfence();
    __syncthreads();
    if (threadIdx.x == 0)
        __hip_atomic_fetch_add(cnt, 1, __ATOMIC_RELEASE, __HIP_MEMORY_SCOPE_AGENT);
}

__device__ __forceinline__ void wait_cnt(int* cnt, int target) {
    if (threadIdx.x == 0) {
        int guard = 0;
        while (__hip_atomic_load(cnt, __ATOMIC_ACQUIRE, __HIP_MEMORY_SCOPE_AGENT) < target) {
            __builtin_amdgcn_s_sleep(2);
            if (++guard > 50000000) break;   // bounded: wrong-answer beats hang
        }
    }
    __syncthreads();
    __threadfence();
}

__global__ __launch_bounds__(256, 4) void fused_all(
    const float* __restrict__ sentence,
    const float* __restrict__ target,
    const float* __restrict__ other,
    const float* __restrict__ scene_desc,
    const float* __restrict__ scene_sent,
    const float* __restrict__ Ws,
    const float* __restrict__ bs,
    const float* __restrict__ W1,
    const float* __restrict__ b1,
    const float* __restrict__ W2,
    const float* __restrict__ b2,
    float* __restrict__ out,
    float* __restrict__ ctx,
    float* __restrict__ final_,
    float* __restrict__ hpart,
    int* __restrict__ cnt1,
    int* __restrict__ cnt2,
    int* __restrict__ cnt3)
{
    const int idx = blockIdx.x;
    const int tid = threadIdx.x;
    __shared__ float sA[2304];        // staging: kb|vbuf / fb / xb / mlp fbuf / hb
    __shared__ float sB[4096];        // redbuf[2][2048] / redf[1024]
    __shared__ double coefA[NCO];
    __shared__ double coefB[NCO];
    __shared__ float partS[NPOW];
    __shared__ float partT[NPOW];
    __shared__ int lastflag;

    if (idx < 192) {
        // ---------------- A: small attention moment scan + eval ----------------
        const bool scene = (idx < 96);
        const int j = scene ? idx : (idx - 96);
        const int b = j / 3;
        const int slice = j - b * 3;
        const float* kp = scene ? (scene_sent + b * 768) : (target + b * 768);
        const float* vp = scene ? (scene_desc + b * 768) : (target + b * 768);
        float* kb = sA;           // [768]
        float* vbuf = sA + 768;   // [768]
        for (int i = tid; i < 768; i += 256) { kb[i] = kp[i]; vbuf[i] = vp[i]; }
        __syncthreads();

        const float g0 = kb[tid] * 0.25f, g1 = kb[tid + 256] * 0.25f, g2 = kb[tid + 512] * 0.25f;
        float p0 = 1.f, p1 = 1.f, p2 = 1.f;

        if (scene) {
            const float v0 = vbuf[tid], v1 = vbuf[tid + 256], v2 = vbuf[tid + 512];
            for (int c = 0; c < 22; ++c) {
                float* buf = sB + (c & 1) * 2048;
                #pragma unroll
                for (int m = 0; m < 4; ++m) {
                    buf[(m * 2 + 0) * 256 + tid] = (p0 + p1) + p2;
                    buf[(m * 2 + 1) * 256 + tid] = fmaf(p0, v0, fmaf(p1, v1, p2 * v2));
                    p0 *= g0; p1 *= g1; p2 *= g2;
                }
                __syncthreads();
                const int n = tid >> 6, s = (tid >> 5) & 1, l = tid & 31;
                const float* src = buf + (n * 2 + s) * 256 + l;
                float acc = ((src[0] + src[32]) + (src[64] + src[96]))
                          + ((src[128] + src[160]) + (src[192] + src[224]));
                acc = red32f(acc);
                if (l == 0) { if (s == 0) partS[c * 4 + n] = acc; else partT[c * 4 + n] = acc; }
            }
        } else {
            for (int c = 0; c < 11; ++c) {
                float* buf = sB + (c & 1) * 2048;
                #pragma unroll
                for (int m = 0; m < 8; ++m) {
                    buf[m * 256 + tid] = (p0 + p1) + p2;
                    p0 *= g0; p1 *= g1; p2 *= g2;
                }
                __syncthreads();
                const int n = tid >> 5, l = tid & 31;
                const float* src = buf + n * 256 + l;
                float acc = ((src[0] + src[32]) + (src[64] + src[96]))
                          + ((src[128] + src[160]) + (src[192] + src[224]));
                acc = red32f(acc);
                if (l == 0) partS[c * 8 + n] = acc;
            }
        }
        __syncthreads();

        if (tid < NCO) {
            double fact = 1.0;
            for (int i = 2; i <= tid; ++i) fact *= (double)i;
            const double inv = 1.0 / fact;
            coefA[tid] = (double)partS[tid] * inv;
            coefB[tid] = scene ? ((double)partT[tid] * inv) : ((double)partS[tid + 1] * inv);
        }
        __syncthreads();

        const int r = slice * 256 + tid;
        const double x = 4.0 * (double)(scene ? kb[r] : other[b * 768 + r]);
        double den = coefA[NCO - 1], num = coefB[NCO - 1];
        for (int n = NCO - 2; n >= 0; --n) {
            den = fma(den, x, coefA[n]);
            num = fma(num, x, coefB[n]);
        }
        ctx[b * 1536 + (scene ? 0 : 768) + r] = (float)(scene ? (num / den) : (4.0 * num / den));
        signal_cnt(&cnt1[b]);

    } else if (idx < 480) {
        // ---------------- B: fused self-attention slice ----------------
        const int j = idx - 192;
        const int b = j / 9;
        const int y = j - b * 9;
        wait_cnt(&cnt1[b], 6);

        float* fb = sA;
        for (int i = tid; i < 2304; i += 256)
            fb[i] = (i < 768) ? sentence[b * 768 + i] : ctx[b * 1536 + (i - 768)];
        __syncthreads();

        float g[9], pw[9];
        #pragma unroll
        for (int k = 0; k < 9; ++k) { g[k] = fb[tid + 256 * k] * 0.25f; pw[k] = 1.f; }

        for (int c = 0; c < 11; ++c) {
            float* buf = sB + (c & 1) * 2048;
            #pragma unroll
            for (int m = 0; m < 8; ++m) {
                buf[m * 256 + tid] = (((pw[0] + pw[1]) + (pw[2] + pw[3]))
                                    + ((pw[4] + pw[5]) + (pw[6] + pw[7]))) + pw[8];
                #pragma unroll
                for (int k = 0; k < 9; ++k) pw[k] *= g[k];
            }
            __syncthreads();
            const int n = tid >> 5, l = tid & 31;
            const float* src = buf + n * 256 + l;
            float acc = ((src[0] + src[32]) + (src[64] + src[96]))
                      + ((src[128] + src[160]) + (src[192] + src[224]));
            acc = red32f(acc);
            if (l == 0) partS[c * 8 + n] = acc;
        }
        __syncthreads();

        if (tid < NCO) {
            double fact = 1.0;
            for (int i = 2; i <= tid; ++i) fact *= (double)i;
            const double inv = 1.0 / fact;
            coefA[tid] = (double)partS[tid] * inv;
            coefB[tid] = (double)partS[tid + 1] * inv;
        }
        __syncthreads();

        const int r = y * 256 + tid;
        const double x = 4.0 * (double)fb[r];
        double den = coefA[NCO - 1], num = coefB[NCO - 1];
        for (int n = NCO - 2; n >= 0; --n) {
            den = fma(den, x, coefA[n]);
            num = fma(num, x, coefB[n]);
        }
        final_[b * 3840 + r] = (float)(4.0 * num / den);
        signal_cnt(&cnt2[b]);

    } else if (idx < 576) {
        // ---------------- B: shared projection ----------------
        const int j = idx - 480;
        const int b = j / 3;
        const int p = j - b * 3;
        const float* xsrc;
        if (p == 0) {
            xsrc = sentence + b * 768;
        } else {
            wait_cnt(&cnt1[b], 6);
            xsrc = ctx + b * 1536 + (p - 1) * 768;
        }
        float* xb = sA;
        float* redf = sB;
        for (int i = tid; i < 768; i += 256) xb[i] = xsrc[i];
        __syncthreads();

        const int g = tid >> 7;        // 0..1
        const int q = tid & 127;
        const float4* __restrict__ Wv = (const float4*)Ws;   // [768][128]
        float ax = 0.f, ay = 0.f, az = 0.f, aw = 0.f;
        #pragma unroll 8
        for (int k = g; k < 768; k += 2) {
            const float xv = xb[k];
            const float4 w = Wv[k * 128 + q];
            ax += xv * w.x; ay += xv * w.y; az += xv * w.z; aw += xv * w.w;
        }
        redf[g * 512 + q * 4 + 0] = ax;
        redf[g * 512 + q * 4 + 1] = ay;
        redf[g * 512 + q * 4 + 2] = az;
        redf[g * 512 + q * 4 + 3] = aw;
        __syncthreads();

        float* dst = final_ + b * 3840 + 2304 + p * 512;
        dst[tid]       = bs[tid]       + redf[tid]       + redf[512 + tid];
        dst[tid + 256] = bs[tid + 256] + redf[tid + 256] + redf[512 + tid + 256];
        signal_cnt(&cnt2[b]);

    } else {
        // ---------------- C: MLP chunk (+ last-block tail) ----------------
        const int j = idx - 576;
        const int b = j >> 3;
        const int c = j & 7;
        wait_cnt(&cnt2[b], 12);

        const int base = c * 480;
        float* fbuf = sA;
        for (int i = tid; i < 480; i += 256) fbuf[i] = final_[b * 3840 + base + i];
        __syncthreads();

        float acc = 0.f;
        const float* Wcol = W1 + base * 256 + tid;
        #pragma unroll 8
        for (int k = 0; k < 480; ++k)
            acc = fmaf(fbuf[k], Wcol[k * 256], acc);
        hpart[(b * 8 + c) * 256 + tid] = acc;

        __threadfence();
        __syncthreads();
        if (tid == 0) {
            const int old = __hip_atomic_fetch_add(&cnt3[b], 1, __ATOMIC_ACQ_REL,
                                                   __HIP_MEMORY_SCOPE_AGENT);
            lastflag = (old == 7) ? 1 : 0;
        }
        __syncthreads();
        if (lastflag) {
            __threadfence();
            float s = b1[tid];
            #pragma unroll
            for (int cc = 0; cc < 8; ++cc) s += hpart[(b * 8 + cc) * 256 + tid];
            sA[tid] = fmaxf(s, 0.f);
            __syncthreads();

            const int w = tid >> 6;
            const int lane = tid & 63;
            for (int o = w; o < 7; o += 4) {
                float a = 0.f;
                #pragma unroll
                for (int cc = lane; cc < 256; cc += 64)
                    a += sA[cc] * W2[cc * 7 + o];
                #pragma unroll
                for (int off = 32; off > 0; off >>= 1)
                    a += __shfl_down(a, off, 64);
                if (lane == 0)
                    out[b * 7 + o] = 1.f / (1.f + __expf(-(a + b2[o])));
            }
        }
    }
}

extern "C" void kernel_launch(void* const* d_in, const int* in_sizes, int n_in,
                              void* d_out, int out_size, void* d_ws, size_t ws_size,
                              hipStream_t stream) {
    const float* sentence   = (const float*)d_in[0];
    const float* target     = (const float*)d_in[1];
    const float* other      = (const float*)d_in[2];
    const float* scene_desc = (const float*)d_in[3];
    const float* scene_sent = (const float*)d_in[4];
    const float* Ws         = (const float*)d_in[5];
    const float* bs         = (const float*)d_in[6];
    const float* W1         = (const float*)d_in[7];
    const float* b1         = (const float*)d_in[8];
    const float* W2         = (const float*)d_in[9];
    const float* b2         = (const float*)d_in[10];
    float* out = (float*)d_out;

    float* ctx    = (float*)d_ws;             // 32*1536
    float* final_ = ctx + 32 * 1536;          // 32*3840
    float* hpart  = final_ + 32 * 3840;       // 32*8*256
    int*   cnts   = (int*)(hpart + 32 * 8 * 256);  // 96 ints
    int* cnt1 = cnts;
    int* cnt2 = cnts + 32;
    int* cnt3 = cnts + 64;

    (void)hipMemsetAsync(cnts, 0, 96 * sizeof(int), stream);
    fused_all<<<832, 256, 0, stream>>>(sentence, target, other, scene_desc, scene_sent,
                                       Ws, bs, W1, b1, W2, b2, out,
                                       ctx, final_, hpart, cnt1, cnt2, cnt3);
}

// Round 15
// 120.309 us; speedup vs baseline: 3.2764x; 3.2764x over previous
//
#include <hip/hip_runtime.h>
#include <math.h>

#define NPOW 88
#define NCO  85

// Moment-method attention (d=1): e^{qf} = sum_n (qf)^n/n! -> per batch power sums
// once, then per-row polynomial eval. Scan in f32 on g=f/4; coefs+Horner in f64.
//
// ws layout: ctx[32*1536] | final[32*3840] | hpart[32*8*256] | cnt3[32]
// 3 dispatches: k1 (small attns + proj0), k2 (fused attn + proj1/2, zeroes cnt3),
//               k3 (mlp chunks + no-wait last-block tail).

__device__ __forceinline__ float red32f(float x) {
    x += __shfl_xor(x, 1, 64);
    x += __shfl_xor(x, 2, 64);
    x += __shfl_xor(x, 4, 64);
    x += __shfl_xor(x, 8, 64);
    x += __shfl_xor(x, 16, 64);
    return x;
}

// ---- projection helper: [768] x [768,512] with 256 threads, 2-way K-split
__device__ __forceinline__ void proj_256(
    const float* __restrict__ xsrc,
    const float* __restrict__ Ws,            // [768, 512]
    const float* __restrict__ bs,            // [512]
    float* __restrict__ dst,
    float* xb,                               // LDS [768]
    float* redf,                             // LDS [1024] = [2][512]
    int tid)
{
    for (int i = tid; i < 768; i += 256) xb[i] = xsrc[i];
    __syncthreads();

    const int g = tid >> 7;        // 0..1
    const int q = tid & 127;       // column quad
    const float4* __restrict__ Wv = (const float4*)Ws;   // [768][128]
    float ax = 0.f, ay = 0.f, az = 0.f, aw = 0.f;
    #pragma unroll 8
    for (int k = g; k < 768; k += 2) {
        const float xv = xb[k];
        const float4 w = Wv[k * 128 + q];
        ax += xv * w.x; ay += xv * w.y; az += xv * w.z; aw += xv * w.w;
    }
    redf[g * 512 + q * 4 + 0] = ax;
    redf[g * 512 + q * 4 + 1] = ay;
    redf[g * 512 + q * 4 + 2] = az;
    redf[g * 512 + q * 4 + 3] = aw;
    __syncthreads();

    dst[tid]       = bs[tid]       + redf[tid]       + redf[512 + tid];
    dst[tid + 256] = bs[tid + 256] + redf[tid + 256] + redf[512 + tid + 256];
}

// K1: grid (32,7), 256 threads.  y=0..2 scene slices, y=3..5 speaker slices, y=6 proj0.
__global__ __launch_bounds__(256) void k1_small_kernel(
    const float* __restrict__ sentence,
    const float* __restrict__ target,
    const float* __restrict__ other,
    const float* __restrict__ scene_desc,
    const float* __restrict__ scene_sent,
    const float* __restrict__ Ws,
    const float* __restrict__ bs,
    float* __restrict__ ctx,
    float* __restrict__ final_)
{
    const int b = blockIdx.x;
    const int y = blockIdx.y;
    const int tid = threadIdx.x;
    __shared__ float kb[768];
    __shared__ float vbuf[768];
    __shared__ float redbuf[2][2048];
    __shared__ float partS[NPOW];
    __shared__ float partT[NPOW];
    __shared__ double coefA[NCO];
    __shared__ double coefB[NCO];
    __shared__ float redf[1024];

    if (y == 6) {
        proj_256(sentence + b * 768, Ws, bs, final_ + b * 3840 + 2304, kb, redf, tid);
        return;
    }

    const bool scene = (y < 3);
    const float* kp = scene ? (scene_sent + b * 768) : (target + b * 768);
    const float* vp = scene ? (scene_desc + b * 768) : (target + b * 768);
    for (int i = tid; i < 768; i += 256) { kb[i] = kp[i]; vbuf[i] = vp[i]; }
    __syncthreads();

    const float g0 = kb[tid] * 0.25f, g1 = kb[tid + 256] * 0.25f, g2 = kb[tid + 512] * 0.25f;
    float p0 = 1.f, p1 = 1.f, p2 = 1.f;

    if (scene) {
        const float v0 = vbuf[tid], v1 = vbuf[tid + 256], v2 = vbuf[tid + 512];
        for (int c = 0; c < 22; ++c) {
            float* buf = redbuf[c & 1];
            #pragma unroll
            for (int m = 0; m < 4; ++m) {
                buf[(m * 2 + 0) * 256 + tid] = (p0 + p1) + p2;
                buf[(m * 2 + 1) * 256 + tid] = fmaf(p0, v0, fmaf(p1, v1, p2 * v2));
                p0 *= g0; p1 *= g1; p2 *= g2;
            }
            __syncthreads();
            const int n = tid >> 6, s = (tid >> 5) & 1, l = tid & 31;
            const float* src = buf + (n * 2 + s) * 256 + l;
            float acc = ((src[0] + src[32]) + (src[64] + src[96]))
                      + ((src[128] + src[160]) + (src[192] + src[224]));
            acc = red32f(acc);
            if (l == 0) { if (s == 0) partS[c * 4 + n] = acc; else partT[c * 4 + n] = acc; }
        }
    } else {
        for (int c = 0; c < 11; ++c) {
            float* buf = redbuf[c & 1];
            #pragma unroll
            for (int m = 0; m < 8; ++m) {
                buf[m * 256 + tid] = (p0 + p1) + p2;
                p0 *= g0; p1 *= g1; p2 *= g2;
            }
            __syncthreads();
            const int n = tid >> 5, l = tid & 31;
            const float* src = buf + n * 256 + l;
            float acc = ((src[0] + src[32]) + (src[64] + src[96]))
                      + ((src[128] + src[160]) + (src[192] + src[224]));
            acc = red32f(acc);
            if (l == 0) partS[c * 8 + n] = acc;
        }
    }
    __syncthreads();

    if (tid < NCO) {
        double fact = 1.0;
        for (int i = 2; i <= tid; ++i) fact *= (double)i;
        const double inv = 1.0 / fact;
        coefA[tid] = (double)partS[tid] * inv;
        coefB[tid] = scene ? ((double)partT[tid] * inv) : ((double)partS[tid + 1] * inv);
    }
    __syncthreads();

    const int slice = scene ? y : (y - 3);
    const int r = slice * 256 + tid;
    const double x = 4.0 * (double)(scene ? kb[r] : other[b * 768 + r]);
    double den = coefA[NCO - 1], num = coefB[NCO - 1];
    for (int n = NCO - 2; n >= 0; --n) {
        den = fma(den, x, coefA[n]);
        num = fma(num, x, coefB[n]);
    }
    const double ratio = scene ? (num / den) : (4.0 * num / den);
    ctx[b * 1536 + (scene ? 0 : 768) + r] = (float)ratio;
}

// K2: grid (32,11), 256 threads.  y=0..8 fused slices, y=9,10 ctx projections.
// Block (b, y=0) also zeroes cnt3[b] for K3 (visible at the dispatch boundary).
__global__ __launch_bounds__(256) void k2_fused_kernel(
    const float* __restrict__ sentence,
    const float* __restrict__ ctx,
    const float* __restrict__ Ws,
    const float* __restrict__ bs,
    float* __restrict__ final_,
    int* __restrict__ cnt3)
{
    const int b = blockIdx.x;
    const int y = blockIdx.y;
    const int tid = threadIdx.x;
    __shared__ float fb[2304];
    __shared__ float redbuf[2][2048];
    __shared__ float partS[NPOW];
    __shared__ double coefA[NCO];
    __shared__ double coefB[NCO];
    __shared__ float redf[1024];

    if (y >= 9) {
        const int p = y - 8;     // 1 or 2
        proj_256(ctx + b * 1536 + (p - 1) * 768, Ws, bs,
                 final_ + b * 3840 + 2304 + p * 512, fb, redf, tid);
        return;
    }
    if (y == 0 && tid == 0) cnt3[b] = 0;

    for (int i = tid; i < 2304; i += 256)
        fb[i] = (i < 768) ? sentence[b * 768 + i] : ctx[b * 1536 + (i - 768)];
    __syncthreads();

    float g[9], pw[9];
    #pragma unroll
    for (int j = 0; j < 9; ++j) { g[j] = fb[tid + 256 * j] * 0.25f; pw[j] = 1.f; }

    for (int c = 0; c < 11; ++c) {
        float* buf = redbuf[c & 1];
        #pragma unroll
        for (int m = 0; m < 8; ++m) {
            buf[m * 256 + tid] = (((pw[0] + pw[1]) + (pw[2] + pw[3]))
                                + ((pw[4] + pw[5]) + (pw[6] + pw[7]))) + pw[8];
            #pragma unroll
            for (int j = 0; j < 9; ++j) pw[j] *= g[j];
        }
        __syncthreads();
        const int n = tid >> 5, l = tid & 31;
        const float* src = buf + n * 256 + l;
        float acc = ((src[0] + src[32]) + (src[64] + src[96]))
                  + ((src[128] + src[160]) + (src[192] + src[224]));
        acc = red32f(acc);
        if (l == 0) partS[c * 8 + n] = acc;
    }
    __syncthreads();

    if (tid < NCO) {
        double fact = 1.0;
        for (int i = 2; i <= tid; ++i) fact *= (double)i;
        const double inv = 1.0 / fact;
        coefA[tid] = (double)partS[tid] * inv;
        coefB[tid] = (double)partS[tid + 1] * inv;
    }
    __syncthreads();

    const int r = y * 256 + tid;
    const double x = 4.0 * (double)fb[r];
    double den = coefA[NCO - 1], num = coefB[NCO - 1];
    for (int n = NCO - 2; n >= 0; --n) {
        den = fma(den, x, coefA[n]);
        num = fma(num, x, coefB[n]);
    }
    final_[b * 3840 + r] = (float)(4.0 * num / den);
}

// K3: whole MLP. grid (32,8), 1024 threads. Chunk c -> hpart; the LAST block per
// batch to finish (atomic count, no waiting/spinning) does relu + head + sigmoid.
__global__ __launch_bounds__(1024) void k3_mlp_kernel(
    const float* __restrict__ final_,
    const float* __restrict__ W1,   // [3840, 256]
    const float* __restrict__ b1,
    const float* __restrict__ W2,   // [256, 7]
    const float* __restrict__ b2,
    float* __restrict__ hpart,      // [32][8][256]
    int* __restrict__ cnt3,
    float* __restrict__ out)        // [32, 7]
{
    const int b = blockIdx.x;
    const int c = blockIdx.y;
    const int tid = threadIdx.x;
    const int base = c * 480;

    __shared__ float fb[480];
    __shared__ float red[16][256];
    __shared__ int lastflag;
    if (tid < 480) fb[tid] = final_[b * 3840 + base + tid];
    __syncthreads();

    const int g = tid >> 6;         // wave id, 16 waves
    const int q = tid & 63;         // column quad
    const float4* __restrict__ Wv = (const float4*)W1;   // [3840][64]
    float ax = 0.f, ay = 0.f, az = 0.f, aw = 0.f;
    const int l0 = g * 30;
    #pragma unroll 5
    for (int kk = 0; kk < 30; ++kk) {
        const float xv = fb[l0 + kk];
        const float4 w = Wv[(base + l0 + kk) * 64 + q];
        ax += xv * w.x; ay += xv * w.y; az += xv * w.z; aw += xv * w.w;
    }
    red[g][q * 4 + 0] = ax;
    red[g][q * 4 + 1] = ay;
    red[g][q * 4 + 2] = az;
    red[g][q * 4 + 3] = aw;
    __syncthreads();

    if (tid < 256) {
        float s = 0.f;
        #pragma unroll
        for (int g2 = 0; g2 < 16; ++g2) s += red[g2][tid];
        hpart[(b * 8 + c) * 256 + tid] = s;
    }

    // no-wait tail: last block per batch finishes the MLP
    __threadfence();
    __syncthreads();
    if (tid == 0) {
        const int old = __hip_atomic_fetch_add(&cnt3[b], 1, __ATOMIC_ACQ_REL,
                                               __HIP_MEMORY_SCOPE_AGENT);
        lastflag = (old == 7) ? 1 : 0;
    }
    __syncthreads();
    if (lastflag) {
        __threadfence();
        if (tid < 256) {
            float s = b1[tid];
            #pragma unroll
            for (int cc = 0; cc < 8; ++cc) s += hpart[(b * 8 + cc) * 256 + tid];
            fb[tid] = fmaxf(s, 0.f);
        }
        __syncthreads();

        const int w = tid >> 6;
        const int lane = tid & 63;
        if (w < 7) {
            float a = 0.f;
            #pragma unroll
            for (int cc = lane; cc < 256; cc += 64)
                a += fb[cc] * W2[cc * 7 + w];
            #pragma unroll
            for (int off = 32; off > 0; off >>= 1)
                a += __shfl_down(a, off, 64);
            if (lane == 0)
                out[b * 7 + w] = 1.f / (1.f + __expf(-(a + b2[w])));
        }
    }
}

extern "C" void kernel_launch(void* const* d_in, const int* in_sizes, int n_in,
                              void* d_out, int out_size, void* d_ws, size_t ws_size,
                              hipStream_t stream) {
    const float* sentence   = (const float*)d_in[0];
    const float* target     = (const float*)d_in[1];
    const float* other      = (const float*)d_in[2];
    const float* scene_desc = (const float*)d_in[3];
    const float* scene_sent = (const float*)d_in[4];
    const float* Ws         = (const float*)d_in[5];
    const float* bs         = (const float*)d_in[6];
    const float* W1         = (const float*)d_in[7];
    const float* b1         = (const float*)d_in[8];
    const float* W2         = (const float*)d_in[9];
    const float* b2         = (const float*)d_in[10];
    float* out = (float*)d_out;

    float* ctx    = (float*)d_ws;             // 32*1536
    float* final_ = ctx + 32 * 1536;          // 32*3840
    float* hpart  = final_ + 32 * 3840;       // 32*8*256
    int*   cnt3   = (int*)(hpart + 32 * 8 * 256);

    k1_small_kernel<<<dim3(32, 7), 256, 0, stream>>>(sentence, target, other,
                                                     scene_desc, scene_sent,
                                                     Ws, bs, ctx, final_);
    k2_fused_kernel<<<dim3(32, 11), 256, 0, stream>>>(sentence, ctx, Ws, bs, final_, cnt3);
    k3_mlp_kernel<<<dim3(32, 8), 1024, 0, stream>>>(final_, W1, b1, W2, b2,
                                                    hpart, cnt3, out);
}

// Round 16
// 56.184 us; speedup vs baseline: 7.0160x; 2.1413x over previous
//
#include <hip/hip_runtime.h>
#include <math.h>

#define NPOW 88   // power sums S_0..S_87 (g = value/4, scanned in f32)
#define NCO  85   // series coefficients n=0..84 (f64)

// Moment-method d=1 attention, fully fused with the MLP stage-1 partials.
// ws: ctx[32*1536] | mom[32][3][96] (sent, scene_ctx, spkr_ctx moments) | hpart[32][21][256]
// kA: ctx + component moments + proj0 col-chunks (+W1 partials)
// kB: fused-attn slices (+W1 partials) + proj1/2 col-chunks (+W1 partials)
// kC: combine 21 partials, relu, 256x7 head, sigmoid.

__device__ __forceinline__ float red64f(float x) {
    x += __shfl_xor(x, 1, 64);
    x += __shfl_xor(x, 2, 64);
    x += __shfl_xor(x, 4, 64);
    x += __shfl_xor(x, 8, 64);
    x += __shfl_xor(x, 16, 64);
    x += __shfl_xor(x, 32, 64);
    return x;
}

// Sync-free wave-split power-sum scan over a 768-vector in LDS (256 thr = 4 waves).
// Wave w computes S_n for n = w, w+4, ..., w+84. Caller __syncthreads() after.
__device__ __forceinline__ void scan768_S(const float* __restrict__ x,
                                          float* __restrict__ partS, int tid) {
    const int w = tid >> 6, lane = tid & 63;
    float pw[12], g4[12];
    #pragma unroll
    for (int e = 0; e < 12; ++e) {
        const float g  = x[lane + 64 * e] * 0.25f;
        const float g2 = g * g;
        g4[e] = g2 * g2;
        pw[e] = (w == 0) ? 1.f : ((w == 1) ? g : ((w == 2) ? g2 : g2 * g));
    }
    for (int i = 0; i < 22; ++i) {
        float s = ((pw[0] + pw[1]) + (pw[2] + pw[3]))
                + ((pw[4] + pw[5]) + (pw[6] + pw[7]))
                + ((pw[8] + pw[9]) + (pw[10] + pw[11]));
        s = red64f(s);
        if (lane == 0) partS[w + 4 * i] = s;
        #pragma unroll
        for (int e = 0; e < 12; ++e) pw[e] *= g4[e];
    }
}

// Same, plus T_n = sum g^n * v (v unscaled).
__device__ __forceinline__ void scan768_ST(const float* __restrict__ x,
                                           const float* __restrict__ v,
                                           float* __restrict__ partS,
                                           float* __restrict__ partT, int tid) {
    const int w = tid >> 6, lane = tid & 63;
    float pw[12], g4[12], vv[12];
    #pragma unroll
    for (int e = 0; e < 12; ++e) {
        const float g  = x[lane + 64 * e] * 0.25f;
        const float g2 = g * g;
        g4[e] = g2 * g2;
        pw[e] = (w == 0) ? 1.f : ((w == 1) ? g : ((w == 2) ? g2 : g2 * g));
        vv[e] = v[lane + 64 * e];
    }
    for (int i = 0; i < 22; ++i) {
        float s = ((pw[0] + pw[1]) + (pw[2] + pw[3]))
                + ((pw[4] + pw[5]) + (pw[6] + pw[7]))
                + ((pw[8] + pw[9]) + (pw[10] + pw[11]));
        float t = ((pw[0]*vv[0] + pw[1]*vv[1]) + (pw[2]*vv[2] + pw[3]*vv[3]))
                + ((pw[4]*vv[4] + pw[5]*vv[5]) + (pw[6]*vv[6] + pw[7]*vv[7]))
                + ((pw[8]*vv[8] + pw[9]*vv[9]) + (pw[10]*vv[10] + pw[11]*vv[11]));
        s = red64f(s);
        t = red64f(t);
        if (lane == 0) { partS[w + 4 * i] = s; partT[w + 4 * i] = t; }
        #pragma unroll
        for (int e = 0; e < 12; ++e) pw[e] *= g4[e];
    }
}

// kA: grid (32, 6), 256 threads.
//  y=0: scene ctx (scan ST + eval 768 + scan ctx -> mom[1])
//  y=1: speaker ctx (scan S + eval 768 with q=other + scan ctx -> mom[2])
//  y=2..5: proj0 col-chunk c=y-2 (c==0 also scans sentence -> mom[0]) + W1 partial
__global__ __launch_bounds__(256) void kA(
    const float* __restrict__ sentence,
    const float* __restrict__ target,
    const float* __restrict__ other,
    const float* __restrict__ scene_desc,
    const float* __restrict__ scene_sent,
    const float* __restrict__ Ws,
    const float* __restrict__ bs,
    const float* __restrict__ W1,
    float* __restrict__ ctx,
    float* __restrict__ mom,
    float* __restrict__ hpart)
{
    const int b = blockIdx.x, y = blockIdx.y, tid = threadIdx.x;
    __shared__ float xb[768];
    __shared__ float vb2[768];
    __shared__ float cbuf[768];
    __shared__ float partS[NPOW];
    __shared__ float partT[NPOW];
    __shared__ double coefA[NCO];
    __shared__ double coefB[NCO];
    __shared__ float redf[8][128];
    __shared__ float sh[128];

    if (y < 2) {
        const bool scene = (y == 0);
        const float* kp = scene ? (scene_sent + b * 768) : (target + b * 768);
        for (int i = tid; i < 768; i += 256) xb[i] = kp[i];
        if (scene)
            for (int i = tid; i < 768; i += 256) vb2[i] = scene_desc[b * 768 + i];
        __syncthreads();
        if (scene) scan768_ST(xb, vb2, partS, partT, tid);
        else       scan768_S(xb, partS, tid);
        __syncthreads();

        if (tid < NCO) {
            double fact = 1.0;
            for (int i = 2; i <= tid; ++i) fact *= (double)i;
            const double inv = 1.0 / fact;
            coefA[tid] = (double)partS[tid] * inv;
            coefB[tid] = scene ? ((double)partT[tid] * inv)
                               : ((double)partS[tid + 1] * inv);
        }
        __syncthreads();

        #pragma unroll
        for (int j = 0; j < 3; ++j) {
            const int r = tid + 256 * j;
            const double x = 4.0 * (double)(scene ? xb[r] : other[b * 768 + r]);
            double den = coefA[NCO - 1], num = coefB[NCO - 1];
            for (int n = NCO - 2; n >= 0; --n) {
                den = fma(den, x, coefA[n]);
                num = fma(num, x, coefB[n]);
            }
            const float cv = (float)(scene ? (num / den) : (4.0 * num / den));
            ctx[b * 1536 + (scene ? 0 : 768) + r] = cv;
            cbuf[r] = cv;
        }
        __syncthreads();
        scan768_S(cbuf, partS, tid);
        __syncthreads();
        if (tid < NPOW) mom[(b * 3 + (scene ? 1 : 2)) * 96 + tid] = partS[tid];
    } else {
        const int c = y - 2;  // 0..3
        for (int i = tid; i < 768; i += 256) xb[i] = sentence[b * 768 + i];
        __syncthreads();
        if (c == 0) {
            scan768_S(xb, partS, tid);
            __syncthreads();
            if (tid < NPOW) mom[(b * 3 + 0) * 96 + tid] = partS[tid];
        }
        // proj0 cols [c*128, c*128+128): 8-way K-split, float4 col-quads
        const int g = tid >> 5, q = tid & 31;
        const float4* __restrict__ Wv = (const float4*)Ws;   // [768][128]
        float ax = 0.f, ay = 0.f, az = 0.f, aw = 0.f;
        #pragma unroll 8
        for (int k = g; k < 768; k += 8) {
            const float xv = xb[k];
            const float4 wq = Wv[k * 128 + c * 32 + q];
            ax = fmaf(xv, wq.x, ax); ay = fmaf(xv, wq.y, ay);
            az = fmaf(xv, wq.z, az); aw = fmaf(xv, wq.w, aw);
        }
        redf[g][q * 4 + 0] = ax; redf[g][q * 4 + 1] = ay;
        redf[g][q * 4 + 2] = az; redf[g][q * 4 + 3] = aw;
        __syncthreads();
        if (tid < 128) {
            float s = bs[c * 128 + tid];
            #pragma unroll
            for (int g2 = 0; g2 < 8; ++g2) s += redf[g2][tid];
            sh[tid] = s;
        }
        __syncthreads();
        // W1 partial: rows [2304+c*128, +128), col = tid
        const int rowbase = 2304 + c * 128;
        float acc = 0.f;
        #pragma unroll 4
        for (int r = 0; r < 128; ++r)
            acc = fmaf(sh[r], W1[(rowbase + r) * 256 + tid], acc);
        hpart[(b * 21 + 9 + c) * 256 + tid] = acc;
    }
}

// kB: grid (32, 17), 256 threads.
//  y=0..8: fused slice y: moments = mom[0]+mom[1]+mom[2], coef, eval 256 rows, z@W1 partial
//  y=9..16: proj p=1+(j>>2), col-chunk c=j&3, + W1 partial
__global__ __launch_bounds__(256) void kB(
    const float* __restrict__ sentence,
    const float* __restrict__ ctx,
    const float* __restrict__ Ws,
    const float* __restrict__ bs,
    const float* __restrict__ W1,
    const float* __restrict__ mom,
    float* __restrict__ hpart)
{
    const int b = blockIdx.x, y = blockIdx.y, tid = threadIdx.x;
    __shared__ float partS[96];
    __shared__ double coefA[NCO];
    __shared__ double coefB[NCO];
    __shared__ float zb[256];
    __shared__ float xb[768];
    __shared__ float redf[8][128];
    __shared__ float sh[128];

    if (y < 9) {
        if (tid < NPOW)
            partS[tid] = mom[(b * 3 + 0) * 96 + tid] + mom[(b * 3 + 1) * 96 + tid]
                       + mom[(b * 3 + 2) * 96 + tid];
        __syncthreads();
        if (tid < NCO) {
            double fact = 1.0;
            for (int i = 2; i <= tid; ++i) fact *= (double)i;
            const double inv = 1.0 / fact;
            coefA[tid] = (double)partS[tid] * inv;
            coefB[tid] = (double)partS[tid + 1] * inv;
        }
        __syncthreads();
        const int r = y * 256 + tid;
        const float fq = (r < 768) ? sentence[b * 768 + r] : ctx[b * 1536 + r - 768];
        const double x = 4.0 * (double)fq;
        double den = coefA[NCO - 1], num = coefB[NCO - 1];
        for (int n = NCO - 2; n >= 0; --n) {
            den = fma(den, x, coefA[n]);
            num = fma(num, x, coefB[n]);
        }
        zb[tid] = (float)(4.0 * num / den);
        __syncthreads();
        const int rowbase = y * 256;
        float acc = 0.f;
        #pragma unroll 4
        for (int r2 = 0; r2 < 256; ++r2)
            acc = fmaf(zb[r2], W1[(rowbase + r2) * 256 + tid], acc);
        hpart[(b * 21 + y) * 256 + tid] = acc;
    } else {
        const int j = y - 9;
        const int p = 1 + (j >> 2);   // 1: scene_ctx, 2: spkr_ctx
        const int c = j & 3;
        for (int i = tid; i < 768; i += 256) xb[i] = ctx[b * 1536 + (p - 1) * 768 + i];
        __syncthreads();
        const int g = tid >> 5, q = tid & 31;
        const float4* __restrict__ Wv = (const float4*)Ws;
        float ax = 0.f, ay = 0.f, az = 0.f, aw = 0.f;
        #pragma unroll 8
        for (int k = g; k < 768; k += 8) {
            const float xv = xb[k];
            const float4 wq = Wv[k * 128 + c * 32 + q];
            ax = fmaf(xv, wq.x, ax); ay = fmaf(xv, wq.y, ay);
            az = fmaf(xv, wq.z, az); aw = fmaf(xv, wq.w, aw);
        }
        redf[g][q * 4 + 0] = ax; redf[g][q * 4 + 1] = ay;
        redf[g][q * 4 + 2] = az; redf[g][q * 4 + 3] = aw;
        __syncthreads();
        if (tid < 128) {
            float s = bs[c * 128 + tid];
            #pragma unroll
            for (int g2 = 0; g2 < 8; ++g2) s += redf[g2][tid];
            sh[tid] = s;
        }
        __syncthreads();
        const int rowbase = 2304 + p * 512 + c * 128;
        float acc = 0.f;
        #pragma unroll 4
        for (int r = 0; r < 128; ++r)
            acc = fmaf(sh[r], W1[(rowbase + r) * 256 + tid], acc);
        hpart[(b * 21 + 9 + 4 * p + c) * 256 + tid] = acc;
    }
}

// kC: grid 32, 256 threads. Sum 21 partials + b1, relu, 256x7 head, sigmoid.
__global__ __launch_bounds__(256) void kC(
    const float* __restrict__ hpart,
    const float* __restrict__ b1,
    const float* __restrict__ W2,
    const float* __restrict__ b2,
    float* __restrict__ out)
{
    const int b = blockIdx.x, tid = threadIdx.x;
    __shared__ float hb[256];
    float s = b1[tid];
    #pragma unroll
    for (int k = 0; k < 21; ++k) s += hpart[(b * 21 + k) * 256 + tid];
    hb[tid] = fmaxf(s, 0.f);
    __syncthreads();
    const int w = tid >> 6, lane = tid & 63;
    for (int o = w; o < 7; o += 4) {
        float a = 0.f;
        #pragma unroll
        for (int cc = lane; cc < 256; cc += 64)
            a += hb[cc] * W2[cc * 7 + o];
        #pragma unroll
        for (int off = 32; off > 0; off >>= 1)
            a += __shfl_down(a, off, 64);
        if (lane == 0)
            out[b * 7 + o] = 1.f / (1.f + __expf(-(a + b2[o])));
    }
}

extern "C" void kernel_launch(void* const* d_in, const int* in_sizes, int n_in,
                              void* d_out, int out_size, void* d_ws, size_t ws_size,
                              hipStream_t stream) {
    const float* sentence   = (const float*)d_in[0];
    const float* target     = (const float*)d_in[1];
    const float* other      = (const float*)d_in[2];
    const float* scene_desc = (const float*)d_in[3];
    const float* scene_sent = (const float*)d_in[4];
    const float* Ws         = (const float*)d_in[5];
    const float* bs         = (const float*)d_in[6];
    const float* W1         = (const float*)d_in[7];
    const float* b1         = (const float*)d_in[8];
    const float* W2         = (const float*)d_in[9];
    const float* b2         = (const float*)d_in[10];
    float* out = (float*)d_out;

    float* ctx   = (float*)d_ws;              // 32*1536
    float* mom   = ctx + 32 * 1536;           // 32*3*96
    float* hpart = mom + 32 * 3 * 96;         // 32*21*256

    kA<<<dim3(32, 6), 256, 0, stream>>>(sentence, target, other, scene_desc,
                                        scene_sent, Ws, bs, W1, ctx, mom, hpart);
    kB<<<dim3(32, 17), 256, 0, stream>>>(sentence, ctx, Ws, bs, W1, mom, hpart);
    kC<<<32, 256, 0, stream>>>(hpart, b1, W2, b2, out);
}

// Round 17
// 50.487 us; speedup vs baseline: 7.8077x; 1.1128x over previous
//
#include <hip/hip_runtime.h>
#include <math.h>

#define NPOW 80   // power sums computed (n = 0..79 in k2; 0..75 in k1 scan)
#define NCO  72   // series coefficients n=0..71 (tail < 1e-13 for |qf| <= ~20)

// Moment-method d=1 attention: e^{qf} = sum_n (qf)^n/n!.  Per batch: power sums
// S'_n = sum (f/4)^n in f32 (no overflow), coefficients + Horner in f64, x = 4q.
// ws: ctx[32*1536] | final[32*3840] | hpart[32*8*256]
// 4 dispatches (r13 structure): k1 (2 attn blocks + proj0), k2 (9 fused + proj1/2),
// mlp_part, mlp_tail.  No atomics, no fences.

__device__ __forceinline__ float red64f(float x) {
    x += __shfl_xor(x, 1, 64);
    x += __shfl_xor(x, 2, 64);
    x += __shfl_xor(x, 4, 64);
    x += __shfl_xor(x, 8, 64);
    x += __shfl_xor(x, 16, 64);
    x += __shfl_xor(x, 32, 64);
    return x;
}

// Sync-free wave-split power-sum scan of a 768-vector (256 thr = 4 waves).
// Wave w computes S_n for n = w + 4i, i = 0..18 (covers n <= 75). Caller syncs.
__device__ __forceinline__ void scan768_S(const float* __restrict__ x,
                                          float* __restrict__ partS, int tid) {
    const int w = tid >> 6, lane = tid & 63;
    float pw[12], g4[12];
    #pragma unroll
    for (int e = 0; e < 12; ++e) {
        const float g  = x[lane + 64 * e] * 0.25f;
        const float g2 = g * g;
        g4[e] = g2 * g2;
        pw[e] = (w == 0) ? 1.f : ((w == 1) ? g : ((w == 2) ? g2 : g2 * g));
    }
    for (int i = 0; i < 19; ++i) {
        float s = ((pw[0] + pw[1]) + (pw[2] + pw[3]))
                + ((pw[4] + pw[5]) + (pw[6] + pw[7]))
                + ((pw[8] + pw[9]) + (pw[10] + pw[11]));
        s = red64f(s);
        if (lane == 0) partS[w + 4 * i] = s;
        #pragma unroll
        for (int e = 0; e < 12; ++e) pw[e] *= g4[e];
    }
}

// Same plus T_n = sum g^n * v (v unscaled).
__device__ __forceinline__ void scan768_ST(const float* __restrict__ x,
                                           const float* __restrict__ v,
                                           float* __restrict__ partS,
                                           float* __restrict__ partT, int tid) {
    const int w = tid >> 6, lane = tid & 63;
    float pw[12], g4[12], vv[12];
    #pragma unroll
    for (int e = 0; e < 12; ++e) {
        const float g  = x[lane + 64 * e] * 0.25f;
        const float g2 = g * g;
        g4[e] = g2 * g2;
        pw[e] = (w == 0) ? 1.f : ((w == 1) ? g : ((w == 2) ? g2 : g2 * g));
        vv[e] = v[lane + 64 * e];
    }
    for (int i = 0; i < 19; ++i) {
        float s = ((pw[0] + pw[1]) + (pw[2] + pw[3]))
                + ((pw[4] + pw[5]) + (pw[6] + pw[7]))
                + ((pw[8] + pw[9]) + (pw[10] + pw[11]));
        float t = ((pw[0]*vv[0] + pw[1]*vv[1]) + (pw[2]*vv[2] + pw[3]*vv[3]))
                + ((pw[4]*vv[4] + pw[5]*vv[5]) + (pw[6]*vv[6] + pw[7]*vv[7]))
                + ((pw[8]*vv[8] + pw[9]*vv[9]) + (pw[10]*vv[10] + pw[11]*vv[11]));
        s = red64f(s);
        t = red64f(t);
        if (lane == 0) { partS[w + 4 * i] = s; partT[w + 4 * i] = t; }
        #pragma unroll
        for (int e = 0; e < 12; ++e) pw[e] *= g4[e];
    }
}

// ---- projection helper: [768] x [768,512] with 256 threads, 2-way K-split
__device__ __forceinline__ void proj_256(
    const float* __restrict__ xsrc,
    const float* __restrict__ Ws,            // [768, 512]
    const float* __restrict__ bs,            // [512]
    float* __restrict__ dst,
    float* xb,                               // LDS [768]
    float* redf,                             // LDS [1024]
    int tid)
{
    for (int i = tid; i < 768; i += 256) xb[i] = xsrc[i];
    __syncthreads();

    const int g = tid >> 7;        // 0..1
    const int q = tid & 127;       // column quad
    const float4* __restrict__ Wv = (const float4*)Ws;   // [768][128]
    float ax = 0.f, ay = 0.f, az = 0.f, aw = 0.f;
    #pragma unroll 8
    for (int k = g; k < 768; k += 2) {
        const float xv = xb[k];
        const float4 w = Wv[k * 128 + q];
        ax += xv * w.x; ay += xv * w.y; az += xv * w.z; aw += xv * w.w;
    }
    redf[g * 512 + q * 4 + 0] = ax;
    redf[g * 512 + q * 4 + 1] = ay;
    redf[g * 512 + q * 4 + 2] = az;
    redf[g * 512 + q * 4 + 3] = aw;
    __syncthreads();

    dst[tid]       = bs[tid]       + redf[tid]       + redf[512 + tid];
    dst[tid + 256] = bs[tid + 256] + redf[tid + 256] + redf[512 + tid + 256];
}

// K1: grid (32,3), 256 threads.
//  y=0: scene ctx  (sync-free scan ST + eval all 768 rows, 3/thread)
//  y=1: speaker ctx (sync-free scan S + eval 768 rows with q=other)
//  y=2: sentence projection
__global__ __launch_bounds__(256) void k1_small_kernel(
    const float* __restrict__ sentence,
    const float* __restrict__ target,
    const float* __restrict__ other,
    const float* __restrict__ scene_desc,
    const float* __restrict__ scene_sent,
    const float* __restrict__ Ws,
    const float* __restrict__ bs,
    float* __restrict__ ctx,
    float* __restrict__ final_)
{
    const int b = blockIdx.x, y = blockIdx.y, tid = threadIdx.x;
    __shared__ float xb[768];
    __shared__ float vbuf[768];
    __shared__ float partS[NPOW];
    __shared__ float partT[NPOW];
    __shared__ double coefA[NCO];
    __shared__ double coefB[NCO];
    __shared__ float redf[1024];

    if (y == 2) {
        proj_256(sentence + b * 768, Ws, bs, final_ + b * 3840 + 2304, xb, redf, tid);
        return;
    }

    const bool scene = (y == 0);
    const float* kp = scene ? (scene_sent + b * 768) : (target + b * 768);
    for (int i = tid; i < 768; i += 256) xb[i] = kp[i];
    if (scene)
        for (int i = tid; i < 768; i += 256) vbuf[i] = scene_desc[b * 768 + i];
    __syncthreads();
    if (scene) scan768_ST(xb, vbuf, partS, partT, tid);
    else       scan768_S(xb, partS, tid);
    __syncthreads();

    if (tid < NCO) {
        double fact = 1.0;
        for (int i = 2; i <= tid; ++i) fact *= (double)i;
        const double inv = 1.0 / fact;
        coefA[tid] = (double)partS[tid] * inv;
        coefB[tid] = scene ? ((double)partT[tid] * inv)
                           : ((double)partS[tid + 1] * inv);
    }
    __syncthreads();

    double q[3], num[3], den[3];
    #pragma unroll
    for (int j = 0; j < 3; ++j) {
        const int r = tid + 256 * j;
        q[j] = 4.0 * (double)(scene ? xb[r] : other[b * 768 + r]);
        den[j] = coefA[NCO - 1];
        num[j] = coefB[NCO - 1];
    }
    for (int n = NCO - 2; n >= 0; --n) {
        const double a = coefA[n], cc = coefB[n];
        #pragma unroll
        for (int j = 0; j < 3; ++j) {
            den[j] = fma(den[j], q[j], a);
            num[j] = fma(num[j], q[j], cc);
        }
    }
    #pragma unroll
    for (int j = 0; j < 3; ++j) {
        const double ratio = scene ? (num[j] / den[j]) : (4.0 * num[j] / den[j]);
        ctx[b * 1536 + (scene ? 0 : 768) + tid + 256 * j] = (float)ratio;
    }
}

// K2: grid (32,11), 256 threads.  y=0..8 fused slices, y=9,10 ctx projections.
__global__ __launch_bounds__(256) void k2_fused_kernel(
    const float* __restrict__ sentence,
    const float* __restrict__ ctx,
    const float* __restrict__ Ws,
    const float* __restrict__ bs,
    float* __restrict__ final_)
{
    const int b = blockIdx.x, y = blockIdx.y, tid = threadIdx.x;
    __shared__ float fb[2304];
    __shared__ float redbuf[2][2048];
    __shared__ float partS[NPOW];
    __shared__ double coefA[NCO];
    __shared__ double coefB[NCO];
    __shared__ float redf[1024];

    if (y >= 9) {
        const int p = y - 8;     // 1 or 2
        proj_256(ctx + b * 1536 + (p - 1) * 768, Ws, bs,
                 final_ + b * 3840 + 2304 + p * 512, fb, redf, tid);
        return;
    }

    for (int i = tid; i < 2304; i += 256)
        fb[i] = (i < 768) ? sentence[b * 768 + i] : ctx[b * 1536 + (i - 768)];
    __syncthreads();

    float g[9], pw[9];
    #pragma unroll
    for (int j = 0; j < 9; ++j) { g[j] = fb[tid + 256 * j] * 0.25f; pw[j] = 1.f; }

    for (int c = 0; c < 10; ++c) {
        float* buf = redbuf[c & 1];
        #pragma unroll
        for (int m = 0; m < 8; ++m) {
            buf[m * 256 + tid] = (((pw[0] + pw[1]) + (pw[2] + pw[3]))
                                + ((pw[4] + pw[5]) + (pw[6] + pw[7]))) + pw[8];
            #pragma unroll
            for (int j = 0; j < 9; ++j) pw[j] *= g[j];
        }
        __syncthreads();
        const int n = tid >> 5, l = tid & 31;
        const float* src = buf + n * 256 + l;
        float acc = ((src[0] + src[32]) + (src[64] + src[96]))
                  + ((src[128] + src[160]) + (src[192] + src[224]));
        acc += __shfl_xor(acc, 1, 64);
        acc += __shfl_xor(acc, 2, 64);
        acc += __shfl_xor(acc, 4, 64);
        acc += __shfl_xor(acc, 8, 64);
        acc += __shfl_xor(acc, 16, 64);
        if (l == 0) partS[c * 8 + n] = acc;
    }
    __syncthreads();

    if (tid < NCO) {
        double fact = 1.0;
        for (int i = 2; i <= tid; ++i) fact *= (double)i;
        const double inv = 1.0 / fact;
        coefA[tid] = (double)partS[tid] * inv;
        coefB[tid] = (double)partS[tid + 1] * inv;
    }
    __syncthreads();

    const int r = y * 256 + tid;
    const double x = 4.0 * (double)fb[r];
    double den = coefA[NCO - 1], num = coefB[NCO - 1];
    for (int n = NCO - 2; n >= 0; --n) {
        den = fma(den, x, coefA[n]);
        num = fma(num, x, coefB[n]);
    }
    final_[b * 3840 + r] = (float)(4.0 * num / den);
}

// MLP stage 1, K-split across blocks: grid (32,8), 1024 threads.
__global__ __launch_bounds__(1024) void mlp_part_kernel(
    const float* __restrict__ final_,
    const float* __restrict__ W1,   // [3840, 256]
    float* __restrict__ hpart)      // [32][8][256]
{
    const int b = blockIdx.x;
    const int c = blockIdx.y;
    const int tid = threadIdx.x;
    const int base = c * 480;

    __shared__ float fb[480];
    __shared__ float red[16][256];
    if (tid < 480) fb[tid] = final_[b * 3840 + base + tid];
    __syncthreads();

    const int g = tid >> 6;         // wave id, 16 waves
    const int q = tid & 63;         // column quad
    const float4* __restrict__ Wv = (const float4*)W1;   // [3840][64]
    float ax = 0.f, ay = 0.f, az = 0.f, aw = 0.f;
    const int l0 = g * 30;
    #pragma unroll 5
    for (int kk = 0; kk < 30; ++kk) {
        const float xv = fb[l0 + kk];
        const float4 w = Wv[(base + l0 + kk) * 64 + q];
        ax += xv * w.x; ay += xv * w.y; az += xv * w.z; aw += xv * w.w;
    }
    red[g][q * 4 + 0] = ax;
    red[g][q * 4 + 1] = ay;
    red[g][q * 4 + 2] = az;
    red[g][q * 4 + 3] = aw;
    __syncthreads();

    if (tid < 256) {
        float s = 0.f;
        #pragma unroll
        for (int g2 = 0; g2 < 16; ++g2) s += red[g2][tid];
        hpart[(b * 8 + c) * 256 + tid] = s;
    }
}

// MLP tail: combine K-partials, relu, [256x7] head, sigmoid. grid 32, 512 threads.
__global__ __launch_bounds__(512) void mlp_tail_kernel(
    const float* __restrict__ hpart,
    const float* __restrict__ b1,
    const float* __restrict__ W2,   // [256, 7]
    const float* __restrict__ b2,
    float* __restrict__ out)        // [32, 7]
{
    const int b = blockIdx.x;
    const int tid = threadIdx.x;

    __shared__ float hb[256];
    if (tid < 256) {
        float s = b1[tid];
        #pragma unroll
        for (int c = 0; c < 8; ++c) s += hpart[(b * 8 + c) * 256 + tid];
        hb[tid] = fmaxf(s, 0.f);
    }
    __syncthreads();

    const int w = tid >> 6;
    const int lane = tid & 63;
    if (w < 7) {
        float a = 0.f;
        #pragma unroll
        for (int c = lane; c < 256; c += 64)
            a += hb[c] * W2[c * 7 + w];
        #pragma unroll
        for (int off = 32; off > 0; off >>= 1)
            a += __shfl_down(a, off, 64);
        if (lane == 0)
            out[b * 7 + w] = 1.f / (1.f + __expf(-(a + b2[w])));
    }
}

extern "C" void kernel_launch(void* const* d_in, const int* in_sizes, int n_in,
                              void* d_out, int out_size, void* d_ws, size_t ws_size,
                              hipStream_t stream) {
    const float* sentence   = (const float*)d_in[0];
    const float* target     = (const float*)d_in[1];
    const float* other      = (const float*)d_in[2];
    const float* scene_desc = (const float*)d_in[3];
    const float* scene_sent = (const float*)d_in[4];
    const float* Ws         = (const float*)d_in[5];
    const float* bs         = (const float*)d_in[6];
    const float* W1         = (const float*)d_in[7];
    const float* b1         = (const float*)d_in[8];
    const float* W2         = (const float*)d_in[9];
    const float* b2         = (const float*)d_in[10];
    float* out = (float*)d_out;

    float* ctx    = (float*)d_ws;             // 32*1536
    float* final_ = ctx + 32 * 1536;          // 32*3840
    float* hpart  = final_ + 32 * 3840;       // 32*8*256

    k1_small_kernel<<<dim3(32, 3), 256, 0, stream>>>(sentence, target, other,
                                                     scene_desc, scene_sent,
                                                     Ws, bs, ctx, final_);
    k2_fused_kernel<<<dim3(32, 11), 256, 0, stream>>>(sentence, ctx, Ws, bs, final_);
    mlp_part_kernel<<<dim3(32, 8), 1024, 0, stream>>>(final_, W1, hpart);
    mlp_tail_kernel<<<32, 512, 0, stream>>>(hpart, b1, W2, b2, out);
}